// Round 11
// baseline (278.766 us; speedup 1.0000x reference)
//
#include <hip/hip_runtime.h>

typedef __bf16 bf16;
typedef __bf16 bf16x4 __attribute__((ext_vector_type(4)));
typedef __bf16 bf16x8 __attribute__((ext_vector_type(8)));
typedef float  f32x4  __attribute__((ext_vector_type(4)));

#define TOKENS 16384
#define D_IN   4096
#define D_OUT  4096
#define RANK   512

// Async global->LDS, 16B per lane. LDS dest wave-uniform base + lane*16;
// global SOURCE is per-lane (swizzles applied by permuting the source).
__device__ inline void gload_lds16(const void* g, void* l) {
    __builtin_amdgcn_global_load_lds((const __attribute__((address_space(1))) void*)g,
                                     (__attribute__((address_space(3))) void*)l,
                                     16, 0, 0);
}

// ---------------------------------------------------------------------------
// Prep 1: Vst[r][k'] = bf16(V[k][r] * sigma[r]), PRE-SWIZZLED (verified:
//   conflicts -> 0). Within each 64-k block: k -> k^((r&7)<<3).
// ---------------------------------------------------------------------------
__global__ __launch_bounds__(256) void vt_scale(const float* __restrict__ V,
                                                const float* __restrict__ sg,
                                                bf16* __restrict__ Vst) {
    __shared__ float tile[64][65];
    const int tx = threadIdx.x & 63;
    const int ty = threadIdx.x >> 6;
    const int kb = blockIdx.x * 64;
    const int rb = blockIdx.y * 64;
    const float s = sg[rb + tx];
#pragma unroll
    for (int i = ty; i < 64; i += 4)
        tile[i][tx] = V[(size_t)(kb + i) * RANK + rb + tx] * s;
    __syncthreads();
#pragma unroll
    for (int i = ty; i < 64; i += 4) {
        int r = rb + i;
        int kp = kb + (tx ^ ((r & 7) << 3));
        Vst[(size_t)r * D_IN + kp] = (bf16)tile[tx][i];
    }
}

// ---------------------------------------------------------------------------
// Prep 2: Ub[n][k'] = bf16(U[n][k]), PRE-SWIZZLED for GEMM2's B staging.
// ---------------------------------------------------------------------------
__global__ __launch_bounds__(256) void cvt_u_swz(const float* __restrict__ U,
                                                 bf16* __restrict__ Ub) {
    int g = blockIdx.x * 256 + threadIdx.x;      // 8-elem chunk id
    int n = g >> 6;
    int c = g & 63;
    int blk = c >> 3, q = c & 7;
    const float* src = U + (size_t)n * RANK + c * 8;
    f32x4 v0 = *(const f32x4*)src;
    f32x4 v1 = *(const f32x4*)(src + 4);
    bf16x8 b;
    b[0] = (bf16)v0[0]; b[1] = (bf16)v0[1]; b[2] = (bf16)v0[2]; b[3] = (bf16)v0[3];
    b[4] = (bf16)v1[0]; b[5] = (bf16)v1[1]; b[6] = (bf16)v1[2]; b[7] = (bf16)v1[3];
    *(bf16x8*)(Ub + (size_t)n * RANK + blk * 64 + ((q ^ (n & 7)) * 8)) = b;
}

// ---------------------------------------------------------------------------
// GEMM1 v2 — staged-bytes-minimized: P[s] = bf16( x[:,s*1024:+1024] @ VstT ).
//   BM=256, BN=256, BK=64, splitK=4 -> staged A = 2x|x| = 512 MB (vs r4's
//   1 GB), B = 64x4 MB = 256 MB (vs 512). Grid 512 (64 m x 2 n x 4 splits).
//   512 thr = 8 waves (2M x 4N), wave tile 128x64 -> 64 MFMA/wave per
//   barrier pair (2x r4 density). r4-proven 2-phase loop; reg-staged bf16-A
//   (r4-equal-fast); verified XOR swizzles on both LDS tiles. Partials bf16.
// ---------------------------------------------------------------------------
__global__ __launch_bounds__(512) void gemm1_v2(const float* __restrict__ A,
                                                const bf16* __restrict__ B,
                                                bf16* __restrict__ P,
                                                int M, int N, int Kfull) {
    __shared__ bf16 Al[256 * 64];   // 32 KB
    __shared__ bf16 Bl[256 * 64];   // 32 KB

    const int t   = threadIdx.x;    // 0..511
    const int l   = t & 63;
    const int wid = t >> 6;
    const int wm  = wid >> 2;       // 0..1 -> rows wm*128
    const int wn  = wid & 3;        // 0..3 -> cols wn*64
    const int lr  = l & 15;
    const int kg  = l >> 4;

    // XCD-aware bijective swizzle (nwg=512): XCD x gets swz x*64..x*64+63,
    // i.e. one split and 32 m-tiles x 2 n-tiles -> A-panel L2 reuse across tn.
    const int nwg = gridDim.x;
    const int bid = blockIdx.x;
    const int cpx = nwg >> 3;                 // 64
    const int swz = (bid & 7) * cpx + (bid >> 3);
    const int split = swz >> 7;               // 0..3
    const int tile  = swz & 127;              // 0..127
    const int tm    = (tile >> 1) << 8;       // 64 m-tiles of 256
    const int tn    = (tile & 1) << 8;        // 2 n-tiles of 256
    const int kbase = split << 10;            // 1024 per split
    const int Ks    = 1024;

    // A staging: round c covers rows c*32 + (t>>4); f32 16B-chunk t&15.
    const int arow = t >> 4;                  // 0..31
    const int acg  = t & 15;
    const float* Ap = A + (size_t)(tm + arow) * Kfull + kbase + acg * 4;
    // ds_write: bf16 granule (acg>>1) ^ (row&7), half acg&1; row&7 == arow&7.
    const int awo = (((acg >> 1) ^ (arow & 7)) << 3) + ((acg & 1) << 2);
    // B staging: round c covers rows c*64 + (t>>3); granule t&7 (src pre-swz).
    const bf16* Bp = B + (size_t)(tn + (t >> 3)) * Kfull + kbase + (t & 7) * 8;

    f32x4 acc[8][4] = {};

    for (int kt = 0; kt < Ks; kt += 64) {
        // ---- B via async DMA first (overlaps A's reg round-trip) ----
#pragma unroll
        for (int c = 0; c < 4; ++c)
            gload_lds16(Bp + kt + (size_t)(c * 64) * Kfull, &Bl[(c * 512 + t) * 8]);
        // ---- A: f32 load -> bf16 cvt -> swizzled ds_write ----
        f32x4 ra[8];
#pragma unroll
        for (int c = 0; c < 8; ++c)
            ra[c] = *(const f32x4*)(Ap + kt + (size_t)(c * 32) * Kfull);
#pragma unroll
        for (int c = 0; c < 8; ++c) {
            bf16x4 b = { (bf16)ra[c][0], (bf16)ra[c][1], (bf16)ra[c][2], (bf16)ra[c][3] };
            *(bf16x4*)&Al[(c * 32 + arow) * 64 + awo] = b;
        }
        __syncthreads();

#pragma unroll
        for (int ks = 0; ks < 2; ++ks) {
            const int gx = ((ks * 4 + kg) ^ (lr & 7)) << 3;
            bf16x8 bq[4];
#pragma unroll
            for (int fn = 0; fn < 4; ++fn)
                bq[fn] = *(const bf16x8*)&Bl[(wn * 64 + fn * 16 + lr) * 64 + gx];
#pragma unroll
            for (int fm = 0; fm < 8; ++fm) {
                bf16x8 aq = *(const bf16x8*)&Al[(wm * 128 + fm * 16 + lr) * 64 + gx];
#pragma unroll
                for (int fn = 0; fn < 4; ++fn)
                    acc[fm][fn] = __builtin_amdgcn_mfma_f32_16x16x32_bf16(
                        aq, bq[fn], acc[fm][fn], 0, 0, 0);
            }
        }
        __syncthreads();
    }

    // ---- bf16 partial write (linear): col = lane&15, row = (lane>>4)*4+reg ----
    bf16* Po = P + (size_t)split * M * N;
    const int r0 = tm + wm * 128 + kg * 4;
    const int c0 = tn + wn * 64 + lr;
#pragma unroll
    for (int fm = 0; fm < 8; ++fm)
#pragma unroll
        for (int fn = 0; fn < 4; ++fn)
#pragma unroll
            for (int r = 0; r < 4; ++r)
                Po[(size_t)(r0 + fm * 16 + r) * N + (c0 + fn * 16)] = (bf16)acc[fm][fn][r];
}

// ---------------------------------------------------------------------------
// Reduce: T = bf16(sum of 4 bf16 partials), written PRE-SWIZZLED for gemm2
//   (granule q of each 64-col block -> q ^ (row&7)).
// ---------------------------------------------------------------------------
__global__ __launch_bounds__(256) void reduce_T(const bf16* __restrict__ P,
                                                bf16* __restrict__ T) {
    const size_t slab = (size_t)TOKENS * RANK;
    const int ng = TOKENS * (RANK / 8);           // 1M granules
    const int stride = gridDim.x * 256;
    for (int i = blockIdx.x * 256 + threadIdx.x; i < ng; i += stride) {
        int row = i >> 6;
        int g   = i & 63;
        float s[8] = {0, 0, 0, 0, 0, 0, 0, 0};
#pragma unroll
        for (int sp = 0; sp < 4; ++sp) {
            bf16x8 v = *(const bf16x8*)&P[sp * slab + (size_t)i * 8];
#pragma unroll
            for (int j = 0; j < 8; ++j) s[j] += (float)v[j];
        }
        bf16x8 o;
#pragma unroll
        for (int j = 0; j < 8; ++j) o[j] = (bf16)s[j];
        int blk = g >> 3, q = g & 7;
        *(bf16x8*)&T[(size_t)row * RANK + blk * 64 + ((q ^ (row & 7)) * 8)] = o;
    }
}

// ---------------------------------------------------------------------------
// GEMM2 — 256x256 multi-phase counted pipeline (r9 validated, unchanged).
// ---------------------------------------------------------------------------
__global__ __launch_bounds__(512, 2) void gemm2_8p(const bf16* __restrict__ A,
                                                   const bf16* __restrict__ B,
                                                   float* __restrict__ out,
                                                   int M, int N, int K) {
    __shared__ bf16 Al[2][256 * 64];
    __shared__ bf16 Bl[2][256 * 64];

    const int t   = threadIdx.x;
    const int l   = t & 63;
    const int wid = t >> 6;
    const int wm  = wid >> 2;
    const int wn  = wid & 3;
    const int lr  = l & 15;
    const int kg  = l >> 4;
    const int sxor = (lr & 7) << 3;

    const int nwg = gridDim.x;
    const int bid = blockIdx.x;
    const int cpx = nwg >> 3;
    const int swz = (bid & 7) * cpx + (bid >> 3);
    const int ntn = N >> 8;
    const int tm  = (swz / ntn) << 8;
    const int tn  = (swz % ntn) << 8;

    const bf16* Apt = A + (size_t)(tm + (t >> 3)) * K + (t & 7) * 8;
    const bf16* Bpt = B + (size_t)(tn + (t >> 3)) * K + (t & 7) * 8;
    const int ldst = t * 8;

    const int NT = K >> 6;

    f32x4 acc[8][4] = {};
    bf16x8 aq[4][2], bq[2][2];

#define STAGE(BUF, KT)                                                         \
    _Pragma("unroll") for (int c = 0; c < 4; ++c) {                            \
        gload_lds16(Apt + (KT) + (size_t)(c * 64) * K, &Al[BUF][c * 4096 + ldst]); \
        gload_lds16(Bpt + (KT) + (size_t)(c * 64) * K, &Bl[BUF][c * 4096 + ldst]); \
    }

#define RD_A(BUF, QM)                                                          \
    _Pragma("unroll") for (int f = 0; f < 4; ++f)                              \
    _Pragma("unroll") for (int ks = 0; ks < 2; ++ks)                           \
        aq[f][ks] = *(const bf16x8*)&Al[BUF][(wm * 128 + (QM) * 64 + f * 16 + lr) * 64 + \
                                            ((ks * 32 + kg * 8) ^ sxor)];

#define RD_B(BUF, QN)                                                          \
    _Pragma("unroll") for (int f = 0; f < 2; ++f)                              \
    _Pragma("unroll") for (int ks = 0; ks < 2; ++ks)                           \
        bq[f][ks] = *(const bf16x8*)&Bl[BUF][(wn * 64 + (QN) * 32 + f * 16 + lr) * 64 + \
                                            ((ks * 32 + kg * 8) ^ sxor)];

#define MM(QM, QN)                                                             \
    __builtin_amdgcn_s_setprio(1);                                             \
    _Pragma("unroll") for (int ks = 0; ks < 2; ++ks)                           \
    _Pragma("unroll") for (int fm = 0; fm < 4; ++fm)                           \
    _Pragma("unroll") for (int fn = 0; fn < 2; ++fn)                           \
        acc[(QM) * 4 + fm][(QN) * 2 + fn] = __builtin_amdgcn_mfma_f32_16x16x32_bf16( \
            aq[fm][ks], bq[fn][ks], acc[(QM) * 4 + fm][(QN) * 2 + fn], 0, 0, 0); \
    __builtin_amdgcn_s_setprio(0);

    STAGE(0, 0);
    STAGE(1, 64);
    asm volatile("s_waitcnt vmcnt(8)" ::: "memory");
    __builtin_amdgcn_sched_barrier(0);
    __builtin_amdgcn_s_barrier();
    __builtin_amdgcn_sched_barrier(0);

    for (int i = 0; i < NT; ++i) {
        const int p = i & 1;
        RD_A(p, 0); RD_B(p, 0); MM(0, 0);
        RD_B(p, 1);             MM(0, 1);
        RD_A(p, 1); RD_B(p, 0); MM(1, 0);
        RD_B(p, 1);             MM(1, 1);

        if (i + 1 < NT) {
            __builtin_amdgcn_sched_barrier(0);
            __builtin_amdgcn_s_barrier();
            __builtin_amdgcn_sched_barrier(0);
            if (i + 2 < NT) {
                STAGE(p, (i + 2) * 64);
                asm volatile("s_waitcnt vmcnt(8)" ::: "memory");
            } else {
                asm volatile("s_waitcnt vmcnt(0)" ::: "memory");
            }
            __builtin_amdgcn_sched_barrier(0);
            __builtin_amdgcn_s_barrier();
            __builtin_amdgcn_sched_barrier(0);
        }
    }

    const int r0 = tm + wm * 128 + kg * 4;
    const int c0 = tn + wn * 64 + lr;
#pragma unroll
    for (int fm = 0; fm < 8; ++fm)
#pragma unroll
        for (int fn = 0; fn < 4; ++fn)
#pragma unroll
            for (int r = 0; r < 4; ++r)
                out[(size_t)(r0 + fm * 16 + r) * N + (c0 + fn * 16)] = acc[fm][fn][r];

#undef STAGE
#undef RD_A
#undef RD_B
#undef MM
}

// ---------------------------------------------------------------------------
extern "C" void kernel_launch(void* const* d_in, const int* in_sizes, int n_in,
                              void* d_out, int out_size, void* d_ws, size_t ws_size,
                              hipStream_t stream) {
    const float* x  = (const float*)d_in[0];  // [16384][4096]
    const float* U  = (const float*)d_in[1];  // [4096][512]
    const float* sg = (const float*)d_in[2];  // [512]
    const float* V  = (const float*)d_in[3];  // [4096][512]
    float* out = (float*)d_out;               // [16384][4096] f32

    char* ws = (char*)d_ws;
    bf16* Vst = (bf16*)ws;                    // [512][4096]   = 4 MB (pre-swizzled)
    bf16* Ub  = (bf16*)(ws + (4u << 20));     // [4096][512]   = 4 MB (pre-swizzled)
    bf16* T   = (bf16*)(ws + (8u << 20));     // [16384][512]  = 16 MB (pre-swizzled)
    bf16* P   = (bf16*)(ws + (32u << 20));    // 4x[16384][512] bf16 = 64 MB

    vt_scale<<<dim3(D_IN / 64, RANK / 64), 256, 0, stream>>>(V, sg, Vst);
    cvt_u_swz<<<(D_OUT * RANK / 8) / 256, 256, 0, stream>>>(U, Ub);

    // GEMM1: 256x256 tiles, splitK=4, grid 64*2*4 = 512
    gemm1_v2<<<512, 512, 0, stream>>>(x, Vst, P, TOKENS, RANK, D_IN);

    // T = bf16(P0+P1+P2+P3), pre-swizzled for gemm2
    reduce_T<<<2048, 256, 0, stream>>>(P, T);

    // GEMM2: out = T @ Ub^T (f32), 256x256 counted pipeline, grid 1024
    gemm2_8p<<<(TOKENS / 256) * (D_OUT / 256), 512, 0, stream>>>(
        T, Ub, out, TOKENS, D_OUT, RANK);
}